// Round 2
// baseline (3639.523 us; speedup 1.0000x reference)
//
#include <hip/hip_runtime.h>

// CGGCN: relation-gated edge MLP + segment_sum + relation scatter + path attention.
// Dual-dtype defensive version: device probe of feat decides fp32 vs bf16 I/O
// (flag in ws); all I/O branches wave-uniformly on it. Internal compute fp32.
//
// Edge-MLP folding (W2 = [W2a;W2b;W2c]):
//   msg = (c_t + p[src] + (et ⊙ g[src]) @ C) * norm
//   c_t = et@(W2a+W2b)+b2 (per etype), g = feat@W_w+b_w, p = g@(W2a-W2b), C = W2c.

#define N_PER_C 4096
#define NGR 14
#define NAR 10

typedef unsigned short u16;
typedef unsigned int u32;

__device__ __forceinline__ float b2f(u16 u) {
    union { u32 i; float f; } x; x.i = ((u32)u) << 16; return x.f;
}
__device__ __forceinline__ u16 f2bf(float f) {
    union { float f; u32 i; } x; x.f = f;
    u32 r = x.i + 0x7fff + ((x.i >> 16) & 1);
    return (u16)(r >> 16);
}
__device__ __forceinline__ float LD(const void* p, size_t i, int isf32) {
    return isf32 ? ((const float*)p)[i] : b2f(((const u16*)p)[i]);
}
__device__ __forceinline__ void ST_OUT(void* p, size_t i, float v, int isf32) {
    if (isf32) ((float*)p)[i] = v;
    else ((u16*)p)[i] = f2bf(v);
}

__global__ void k_detect(const u32* __restrict__ featw, int* __restrict__ flag) {
    __shared__ int cnt;
    if (threadIdx.x == 0) cnt = 0;
    __syncthreads();
    u32 w = featw[threadIdx.x];
    u32 lo = w & 0xffffu;
    u32 e = (lo >> 7) & 0xffu;
    if ((e >= 100 && e <= 140) || lo == 0) atomicAdd(&cnt, 1);
    __syncthreads();
    if (threadIdx.x == 0) flag[0] = (cnt < 128) ? 1 : 0;  // 1 => fp32
}

__global__ void k_zero(u32* __restrict__ out, int out_size, const int* __restrict__ flag) {
    int i = blockIdx.x * blockDim.x + threadIdx.x;
    int words = (flag[0] ? out_size : out_size / 2);
    if (i < words) out[i] = 0;
}

__global__ void k0_prep(const void* W_w, const void* b_w, const void* W2, const void* b2v,
                        const void* attn, const void* slw, const void* W_line, const void* b_line,
                        float* Wwf, float* bwf, float* Af, float* Cf, float* cbuf,
                        float* attnf, float* slwf, float* Wlf, float* blf,
                        float* tacc, int taccN, const int* __restrict__ flag) {
    int j = blockIdx.x * blockDim.x + threadIdx.x;   // 0..1023
    int isf32 = flag[0];
    if (j < 1024) {
        int k = j >> 5, c = j & 31;
        Wwf[j]  = LD(W_w, j, isf32);
        slwf[j] = LD(slw, j, isf32);
        Wlf[j]  = LD(W_line, j, isf32);
        Af[j]   = LD(W2, k * 32 + c, isf32) - LD(W2, (32 + k) * 32 + c, isf32);
        Cf[j]   = LD(W2, (64 + k) * 32 + c, isf32);
    }
    if (j < taccN) tacc[j] = 0.f;
    if (j < NAR * 32) {
        attnf[j] = LD(attn, j, isf32);
        int t = j >> 5, c = j & 31;
        float s = LD(b2v, c, isf32);
        for (int k = 0; k < 32; ++k)
            s += LD(attn, t * 32 + k, isf32) *
                 (LD(W2, k * 32 + c, isf32) + LD(W2, (32 + k) * 32 + c, isf32));
        cbuf[j] = s;
    }
    if (j < 32) { bwf[j] = LD(b_w, j, isf32); blf[j] = LD(b_line, j, isf32); }
}

__global__ void k1_node(const void* __restrict__ feat, const float* __restrict__ Wwf,
                        const float* __restrict__ bwf, const float* __restrict__ slwf,
                        const float* __restrict__ Af, void* __restrict__ gp,
                        float* __restrict__ h, int N,
                        const int* __restrict__ flag, int gpf32) {
    int n = blockIdx.x * blockDim.x + threadIdx.x;
    if (n >= N) return;
    int isf32 = flag[0];
    float f[32];
    if (isf32) {
        const float4* fr = (const float4*)((const float*)feat + (size_t)n * 32);
#pragma unroll
        for (int q = 0; q < 8; ++q) {
            float4 v = fr[q];
            f[q * 4 + 0] = v.x; f[q * 4 + 1] = v.y; f[q * 4 + 2] = v.z; f[q * 4 + 3] = v.w;
        }
    } else {
        const uint4* fr = (const uint4*)((const u16*)feat + (size_t)n * 32);
#pragma unroll
        for (int q = 0; q < 4; ++q) {
            uint4 v = fr[q];
            u32 ww[4] = {v.x, v.y, v.z, v.w};
#pragma unroll
            for (int r = 0; r < 4; ++r) {
                f[q * 8 + 2 * r]     = b2f((u16)(ww[r] & 0xffff));
                f[q * 8 + 2 * r + 1] = b2f((u16)(ww[r] >> 16));
            }
        }
    }
    float g[32], hh[32];
#pragma unroll
    for (int j = 0; j < 32; ++j) { g[j] = bwf[j]; hh[j] = 0.f; }
#pragma unroll
    for (int k = 0; k < 32; ++k) {
        float fk = f[k];
#pragma unroll
        for (int j = 0; j < 32; ++j) {
            g[j]  += fk * Wwf[k * 32 + j];
            hh[j] += fk * slwf[k * 32 + j];
        }
    }
    float p[32];
#pragma unroll
    for (int j = 0; j < 32; ++j) p[j] = 0.f;
#pragma unroll
    for (int k = 0; k < 32; ++k) {
        float gk = g[k];
#pragma unroll
        for (int j = 0; j < 32; ++j) p[j] += gk * Af[k * 32 + j];
    }
    if (gpf32) {
        float4* go = (float4*)((float*)gp + (size_t)n * 64);
#pragma unroll
        for (int q = 0; q < 8; ++q)
            go[q] = make_float4(g[q * 4], g[q * 4 + 1], g[q * 4 + 2], g[q * 4 + 3]);
#pragma unroll
        for (int q = 0; q < 8; ++q)
            go[8 + q] = make_float4(p[q * 4], p[q * 4 + 1], p[q * 4 + 2], p[q * 4 + 3]);
    } else {
        u16* go = (u16*)gp + (size_t)n * 64;
#pragma unroll
        for (int j = 0; j < 32; ++j) { go[j] = f2bf(g[j]); go[32 + j] = f2bf(p[j]); }
    }
    float4* ho = (float4*)(h + (size_t)n * 32);
#pragma unroll
    for (int q = 0; q < 8; ++q)
        ho[q] = make_float4(hh[q * 4], hh[q * 4 + 1], hh[q * 4 + 2], hh[q * 4 + 3]);
}

__global__ void k2_edge(const int* __restrict__ src, const int* __restrict__ dst,
                        const int* __restrict__ et, const void* __restrict__ norm,
                        const void* __restrict__ gp, const float* __restrict__ cbuf,
                        const float* __restrict__ attnf, const float* __restrict__ Cf,
                        float* __restrict__ h, int E,
                        const int* __restrict__ flag, int gpf32) {
    int e = blockIdx.x * blockDim.x + threadIdx.x;
    if (e >= E) return;
    int isf32 = flag[0];
    int s = src[e], d = dst[e], t = et[e];
    float nr = LD(norm, e, isf32);
    float gv[32], pv[32];
    if (gpf32) {
        const float4* gps = (const float4*)((const float*)gp + (size_t)s * 64);
#pragma unroll
        for (int q = 0; q < 8; ++q) {
            float4 v = gps[q];
            gv[q * 4] = v.x; gv[q * 4 + 1] = v.y; gv[q * 4 + 2] = v.z; gv[q * 4 + 3] = v.w;
        }
#pragma unroll
        for (int q = 0; q < 8; ++q) {
            float4 v = gps[8 + q];
            pv[q * 4] = v.x; pv[q * 4 + 1] = v.y; pv[q * 4 + 2] = v.z; pv[q * 4 + 3] = v.w;
        }
    } else {
        const u16* gg = (const u16*)gp + (size_t)s * 64;
#pragma unroll
        for (int j = 0; j < 32; ++j) { gv[j] = b2f(gg[j]); pv[j] = b2f(gg[32 + j]); }
    }
    const float4* cb4 = (const float4*)(cbuf + t * 32);
    const float4* at4 = (const float4*)(attnf + t * 32);
    float xg[32], acc[32];
#pragma unroll
    for (int q = 0; q < 8; ++q) {
        float4 av = at4[q];
        xg[q * 4]     = gv[q * 4]     * av.x;
        xg[q * 4 + 1] = gv[q * 4 + 1] * av.y;
        xg[q * 4 + 2] = gv[q * 4 + 2] * av.z;
        xg[q * 4 + 3] = gv[q * 4 + 3] * av.w;
    }
#pragma unroll
    for (int q = 0; q < 8; ++q) {
        float4 cv = cb4[q];
        acc[q * 4]     = cv.x + pv[q * 4];
        acc[q * 4 + 1] = cv.y + pv[q * 4 + 1];
        acc[q * 4 + 2] = cv.z + pv[q * 4 + 2];
        acc[q * 4 + 3] = cv.w + pv[q * 4 + 3];
    }
#pragma unroll
    for (int k = 0; k < 32; ++k) {
        float x = xg[k];
#pragma unroll
        for (int j = 0; j < 32; ++j) acc[j] += x * Cf[k * 32 + j];
    }
    float* hr = h + (size_t)d * 32;
#pragma unroll
    for (int j = 0; j < 32; ++j) atomicAdd(hr + j, acc[j] * nr);
}

__global__ void k3_nf(float* __restrict__ h, const float* __restrict__ Wlf,
                      const float* __restrict__ blf, const int* __restrict__ index2,
                      const int* __restrict__ f2, const int* __restrict__ tar,
                      void* __restrict__ out_bre, float* __restrict__ tacc, int N,
                      const int* __restrict__ flag) {
    int n = blockIdx.x * blockDim.x + threadIdx.x;
    if (n >= N) return;
    int isf32 = flag[0];
    float hr[32];
    const float4* h4 = (const float4*)(h + (size_t)n * 32);
#pragma unroll
    for (int q = 0; q < 8; ++q) {
        float4 v = h4[q];
        hr[q * 4] = v.x; hr[q * 4 + 1] = v.y; hr[q * 4 + 2] = v.z; hr[q * 4 + 3] = v.w;
    }
    float o[32];
#pragma unroll
    for (int j = 0; j < 32; ++j) o[j] = blf[j];
#pragma unroll
    for (int k = 0; k < 32; ++k) {
        float hk = hr[k];
#pragma unroll
        for (int j = 0; j < 32; ++j) o[j] += hk * Wlf[k * 32 + j];
    }
#pragma unroll
    for (int j = 0; j < 32; ++j) o[j] = fmaxf(o[j], 0.f);
    float4* ho = (float4*)(h + (size_t)n * 32);       // in-place: h -> nf
#pragma unroll
    for (int q = 0; q < 8; ++q)
        ho[q] = make_float4(o[q * 4], o[q * 4 + 1], o[q * 4 + 2], o[q * 4 + 3]);
    int b = n / N_PER_C;
    if (index2[n] != 0) {
        int idx = f2[n] + 1;                          // index_offset = 1
        if (idx >= 0 && idx <= NGR) {
            size_t bse = ((size_t)(b * (NGR + 1) + idx)) * 32;
#pragma unroll
            for (int j = 0; j < 32; ++j) ST_OUT(out_bre, bse + j, o[j], isf32);
        }
    }
    if (tar[n] == 1) {
        float* ta = tacc + (size_t)b * 32;
#pragma unroll
        for (int j = 0; j < 32; ++j) atomicAdd(ta + j, o[j]);
    }
}

__global__ __launch_bounds__(256) void k4_attn(const float* __restrict__ nf,
                                               const float* __restrict__ tacc,
                                               const int* __restrict__ index1,
                                               const void* __restrict__ zero_path,
                                               void* __restrict__ out,
                                               size_t off_tar, size_t off_path,
                                               const int* __restrict__ flag) {
    int b = blockIdx.x;
    int tid = threadIdx.x;
    int isf32 = flag[0];
    __shared__ float tg[32];
    __shared__ float red_m[256], red_l[256];
    __shared__ float red_a[256][33];
    if (tid < 32) {
        float v = tacc[(size_t)b * 32 + tid];
        tg[tid] = v;
        ST_OUT(out, off_tar + (size_t)b * 32 + tid, v, isf32);
    }
    __syncthreads();
    float tv[32];
#pragma unroll
    for (int j = 0; j < 32; ++j) tv[j] = tg[j];
    float m = -1e30f, l = 0.f, a[32];
#pragma unroll
    for (int j = 0; j < 32; ++j) a[j] = 0.f;
    for (int r = tid; r < N_PER_C; r += 256) {
        int n = b * N_PER_C + r;
        if (index1[n] == 1) {
            float row[32];
            const float4* nr4 = (const float4*)(nf + (size_t)n * 32);
#pragma unroll
            for (int q = 0; q < 8; ++q) {
                float4 v = nr4[q];
                row[q * 4] = v.x; row[q * 4 + 1] = v.y;
                row[q * 4 + 2] = v.z; row[q * 4 + 3] = v.w;
            }
            float dot = 0.f;
#pragma unroll
            for (int j = 0; j < 32; ++j) dot += row[j] * tv[j];
            if (dot > m) {
                float c = __expf(m - dot);
                l *= c;
#pragma unroll
                for (int j = 0; j < 32; ++j) a[j] *= c;
                m = dot;
            }
            float w = __expf(dot - m);
            l += w;
#pragma unroll
            for (int j = 0; j < 32; ++j) a[j] += w * row[j];
        }
    }
    red_m[tid] = m; red_l[tid] = l;
#pragma unroll
    for (int j = 0; j < 32; ++j) red_a[tid][j] = a[j];
    __syncthreads();
    for (int s = 128; s >= 1; s >>= 1) {
        if (tid < s) {
            float m1 = red_m[tid], m2 = red_m[tid + s];
            float M = fmaxf(m1, m2);
            float c1 = __expf(m1 - M), c2 = __expf(m2 - M);
            red_l[tid] = red_l[tid] * c1 + red_l[tid + s] * c2;
#pragma unroll
            for (int j = 0; j < 32; ++j)
                red_a[tid][j] = red_a[tid][j] * c1 + red_a[tid + s][j] * c2;
            red_m[tid] = M;
        }
        __syncthreads();
    }
    if (tid < 32) {
        float L = red_l[0];
        float o = (L > 0.f) ? (red_a[0][tid] / L) : LD(zero_path, tid, isf32);
        ST_OUT(out, off_path + (size_t)b * 32 + tid, o, isf32);
    }
}

extern "C" void kernel_launch(void* const* d_in, const int* in_sizes, int n_in,
                              void* d_out, int out_size, void* d_ws, size_t ws_size,
                              hipStream_t stream) {
    const void* feat     = d_in[0];
    const void* norm     = d_in[1];
    const void* W_w      = d_in[2];
    const void* b_w      = d_in[3];
    const void* W2       = d_in[4];
    const void* b2v      = d_in[5];
    const void* attn     = d_in[6];
    const void* slw      = d_in[7];
    const void* W_line   = d_in[8];
    const void* b_line   = d_in[9];
    const void* zeroPath = d_in[10];
    const int* src       = (const int*)d_in[11];
    const int* dst       = (const int*)d_in[12];
    const int* etype     = (const int*)d_in[13];
    const int* index1    = (const int*)d_in[14];
    const int* index2    = (const int*)d_in[15];
    const int* f2        = (const int*)d_in[16];
    const int* tar       = (const int*)d_in[17];

    int N  = in_sizes[0] / 32;
    int E  = in_sizes[1];
    int Bn = N / N_PER_C;

    char* base  = (char*)d_ws;
    int* flag   = (int*)base;                      // 64 B reserved
    float* Wwf  = (float*)(base + 64);             // 1024
    float* bwf  = Wwf + 1024;                      // 32
    float* Af   = bwf + 32;                        // 1024
    float* Cf   = Af + 1024;                       // 1024
    float* cbuf = Cf + 1024;                       // 320
    float* attnf= cbuf + NAR * 32;                 // 320
    float* slwf = attnf + NAR * 32;                // 1024
    float* Wlf  = slwf + 1024;                     // 1024
    float* blf  = Wlf + 1024;                      // 32
    float* tacc = blf + 32;                        // Bn*32
    float* h    = tacc + (size_t)Bn * 32;          // N*32
    char*  gp   = (char*)(h + (size_t)N * 32);     // N*64 fp32 or bf16

    size_t fixed_bytes = (size_t)(gp - base);
    int gpf32 = (ws_size >= fixed_bytes + (size_t)N * 64 * 4) ? 1 : 0;

    size_t off_tar  = (size_t)Bn * (NGR + 1) * 32;
    size_t off_path = off_tar + (size_t)Bn * 32;

    k_detect<<<1, 256, 0, stream>>>((const u32*)feat, flag);
    k_zero<<<(out_size + 255) / 256, 256, 0, stream>>>((u32*)d_out, out_size, flag);
    k0_prep<<<4, 256, 0, stream>>>(W_w, b_w, W2, b2v, attn, slw, W_line, b_line,
                                   Wwf, bwf, Af, Cf, cbuf, attnf, slwf, Wlf, blf,
                                   tacc, Bn * 32, flag);
    k1_node<<<(N + 255) / 256, 256, 0, stream>>>(feat, Wwf, bwf, slwf, Af, gp, h, N,
                                                 flag, gpf32);
    k2_edge<<<(E + 255) / 256, 256, 0, stream>>>(src, dst, etype, norm, gp, cbuf,
                                                 attnf, Cf, h, E, flag, gpf32);
    k3_nf<<<(N + 255) / 256, 256, 0, stream>>>(h, Wlf, blf, index2, f2, tar,
                                               d_out, tacc, N, flag);
    k4_attn<<<Bn, 256, 0, stream>>>(h, tacc, index1, zeroPath, d_out,
                                    off_tar, off_path, flag);
}

// Round 3
// 466.212 us; speedup vs baseline: 7.8066x; 7.8066x over previous
//
#include <hip/hip_runtime.h>

// CGGCN: relation-gated edge MLP + segment_sum + relation scatter + path attention.
// Dual-dtype defensive version: device probe of feat decides fp32 vs bf16 I/O
// (flag in ws); all I/O branches wave-uniformly on it. Internal compute fp32.
//
// Edge-MLP folding (W2 = [W2a;W2b;W2c]):
//   msg = (c_t + p[src] + (et ⊙ g[src]) @ C) * norm
//   c_t = et@(W2a+W2b)+b2 (per etype), g = feat@W_w+b_w, p = g@(W2a-W2b), C = W2c.
//
// R3 change: k2's segment-sum atomics are transposed through LDS so each
// 32-lane group issues atomicAdds to 32 CONSECUTIVE floats of one h-row
// (2 cache lines per wave64 atomic instr instead of 64 scattered lines).

#define N_PER_C 4096
#define NGR 14
#define NAR 10
#define EPB 256          // edges per block in k2

typedef unsigned short u16;
typedef unsigned int u32;

__device__ __forceinline__ float b2f(u16 u) {
    union { u32 i; float f; } x; x.i = ((u32)u) << 16; return x.f;
}
__device__ __forceinline__ u16 f2bf(float f) {
    union { float f; u32 i; } x; x.f = f;
    u32 r = x.i + 0x7fff + ((x.i >> 16) & 1);
    return (u16)(r >> 16);
}
__device__ __forceinline__ float LD(const void* p, size_t i, int isf32) {
    return isf32 ? ((const float*)p)[i] : b2f(((const u16*)p)[i]);
}
__device__ __forceinline__ void ST_OUT(void* p, size_t i, float v, int isf32) {
    if (isf32) ((float*)p)[i] = v;
    else ((u16*)p)[i] = f2bf(v);
}

__global__ void k_detect(const u32* __restrict__ featw, int* __restrict__ flag) {
    __shared__ int cnt;
    if (threadIdx.x == 0) cnt = 0;
    __syncthreads();
    u32 w = featw[threadIdx.x];
    u32 lo = w & 0xffffu;
    u32 e = (lo >> 7) & 0xffu;
    if ((e >= 100 && e <= 140) || lo == 0) atomicAdd(&cnt, 1);
    __syncthreads();
    if (threadIdx.x == 0) flag[0] = (cnt < 128) ? 1 : 0;  // 1 => fp32
}

__global__ void k_zero(u32* __restrict__ out, int out_size, const int* __restrict__ flag) {
    int i = blockIdx.x * blockDim.x + threadIdx.x;
    int words = (flag[0] ? out_size : out_size / 2);
    if (i < words) out[i] = 0;
}

__global__ void k0_prep(const void* W_w, const void* b_w, const void* W2, const void* b2v,
                        const void* attn, const void* slw, const void* W_line, const void* b_line,
                        float* Wwf, float* bwf, float* Af, float* Cf, float* cbuf,
                        float* attnf, float* slwf, float* Wlf, float* blf,
                        float* tacc, int taccN, const int* __restrict__ flag) {
    int j = blockIdx.x * blockDim.x + threadIdx.x;   // 0..1023
    int isf32 = flag[0];
    if (j < 1024) {
        int k = j >> 5, c = j & 31;
        Wwf[j]  = LD(W_w, j, isf32);
        slwf[j] = LD(slw, j, isf32);
        Wlf[j]  = LD(W_line, j, isf32);
        Af[j]   = LD(W2, k * 32 + c, isf32) - LD(W2, (32 + k) * 32 + c, isf32);
        Cf[j]   = LD(W2, (64 + k) * 32 + c, isf32);
    }
    if (j < taccN) tacc[j] = 0.f;
    if (j < NAR * 32) {
        attnf[j] = LD(attn, j, isf32);
        int t = j >> 5, c = j & 31;
        float s = LD(b2v, c, isf32);
        for (int k = 0; k < 32; ++k)
            s += LD(attn, t * 32 + k, isf32) *
                 (LD(W2, k * 32 + c, isf32) + LD(W2, (32 + k) * 32 + c, isf32));
        cbuf[j] = s;
    }
    if (j < 32) { bwf[j] = LD(b_w, j, isf32); blf[j] = LD(b_line, j, isf32); }
}

__global__ void k1_node(const void* __restrict__ feat, const float* __restrict__ Wwf,
                        const float* __restrict__ bwf, const float* __restrict__ slwf,
                        const float* __restrict__ Af, void* __restrict__ gp,
                        float* __restrict__ h, int N,
                        const int* __restrict__ flag, int gpf32) {
    int n = blockIdx.x * blockDim.x + threadIdx.x;
    if (n >= N) return;
    int isf32 = flag[0];
    float f[32];
    if (isf32) {
        const float4* fr = (const float4*)((const float*)feat + (size_t)n * 32);
#pragma unroll
        for (int q = 0; q < 8; ++q) {
            float4 v = fr[q];
            f[q * 4 + 0] = v.x; f[q * 4 + 1] = v.y; f[q * 4 + 2] = v.z; f[q * 4 + 3] = v.w;
        }
    } else {
        const uint4* fr = (const uint4*)((const u16*)feat + (size_t)n * 32);
#pragma unroll
        for (int q = 0; q < 4; ++q) {
            uint4 v = fr[q];
            u32 ww[4] = {v.x, v.y, v.z, v.w};
#pragma unroll
            for (int r = 0; r < 4; ++r) {
                f[q * 8 + 2 * r]     = b2f((u16)(ww[r] & 0xffff));
                f[q * 8 + 2 * r + 1] = b2f((u16)(ww[r] >> 16));
            }
        }
    }
    float g[32], hh[32];
#pragma unroll
    for (int j = 0; j < 32; ++j) { g[j] = bwf[j]; hh[j] = 0.f; }
#pragma unroll
    for (int k = 0; k < 32; ++k) {
        float fk = f[k];
#pragma unroll
        for (int j = 0; j < 32; ++j) {
            g[j]  += fk * Wwf[k * 32 + j];
            hh[j] += fk * slwf[k * 32 + j];
        }
    }
    float p[32];
#pragma unroll
    for (int j = 0; j < 32; ++j) p[j] = 0.f;
#pragma unroll
    for (int k = 0; k < 32; ++k) {
        float gk = g[k];
#pragma unroll
        for (int j = 0; j < 32; ++j) p[j] += gk * Af[k * 32 + j];
    }
    if (gpf32) {
        float4* go = (float4*)((float*)gp + (size_t)n * 64);
#pragma unroll
        for (int q = 0; q < 8; ++q)
            go[q] = make_float4(g[q * 4], g[q * 4 + 1], g[q * 4 + 2], g[q * 4 + 3]);
#pragma unroll
        for (int q = 0; q < 8; ++q)
            go[8 + q] = make_float4(p[q * 4], p[q * 4 + 1], p[q * 4 + 2], p[q * 4 + 3]);
    } else {
        u16* go = (u16*)gp + (size_t)n * 64;
#pragma unroll
        for (int j = 0; j < 32; ++j) { go[j] = f2bf(g[j]); go[32 + j] = f2bf(p[j]); }
    }
    float4* ho = (float4*)(h + (size_t)n * 32);
#pragma unroll
    for (int q = 0; q < 8; ++q)
        ho[q] = make_float4(hh[q * 4], hh[q * 4 + 1], hh[q * 4 + 2], hh[q * 4 + 3]);
}

// R3: LDS-transposed coalesced-atomic edge kernel
__global__ __launch_bounds__(256) void k2_edge(const int* __restrict__ src,
                        const int* __restrict__ dst,
                        const int* __restrict__ et, const void* __restrict__ norm,
                        const void* __restrict__ gp, const float* __restrict__ cbuf,
                        const float* __restrict__ attnf, const float* __restrict__ Cf,
                        float* __restrict__ h, int E,
                        const int* __restrict__ flag, int gpf32) {
    __shared__ float acc_s[EPB][33];   // stride 33: conflict-free write & read
    __shared__ int d_s[EPB];
    int tid = threadIdx.x;
    int e = blockIdx.x * EPB + tid;
    int isf32 = flag[0];

    if (e < E) {
        int s = src[e], d = dst[e], t = et[e];
        float nr = LD(norm, e, isf32);
        float gv[32], pv[32];
        if (gpf32) {
            const float4* gps = (const float4*)((const float*)gp + (size_t)s * 64);
#pragma unroll
            for (int q = 0; q < 8; ++q) {
                float4 v = gps[q];
                gv[q * 4] = v.x; gv[q * 4 + 1] = v.y; gv[q * 4 + 2] = v.z; gv[q * 4 + 3] = v.w;
            }
#pragma unroll
            for (int q = 0; q < 8; ++q) {
                float4 v = gps[8 + q];
                pv[q * 4] = v.x; pv[q * 4 + 1] = v.y; pv[q * 4 + 2] = v.z; pv[q * 4 + 3] = v.w;
            }
        } else {
            const u16* gg = (const u16*)gp + (size_t)s * 64;
#pragma unroll
            for (int j = 0; j < 32; ++j) { gv[j] = b2f(gg[j]); pv[j] = b2f(gg[32 + j]); }
        }
        const float4* cb4 = (const float4*)(cbuf + t * 32);
        const float4* at4 = (const float4*)(attnf + t * 32);
        float xg[32], acc[32];
#pragma unroll
        for (int q = 0; q < 8; ++q) {
            float4 av = at4[q];
            xg[q * 4]     = gv[q * 4]     * av.x;
            xg[q * 4 + 1] = gv[q * 4 + 1] * av.y;
            xg[q * 4 + 2] = gv[q * 4 + 2] * av.z;
            xg[q * 4 + 3] = gv[q * 4 + 3] * av.w;
        }
#pragma unroll
        for (int q = 0; q < 8; ++q) {
            float4 cv = cb4[q];
            acc[q * 4]     = cv.x + pv[q * 4];
            acc[q * 4 + 1] = cv.y + pv[q * 4 + 1];
            acc[q * 4 + 2] = cv.z + pv[q * 4 + 2];
            acc[q * 4 + 3] = cv.w + pv[q * 4 + 3];
        }
#pragma unroll
        for (int k = 0; k < 32; ++k) {
            float x = xg[k];
#pragma unroll
            for (int j = 0; j < 32; ++j) acc[j] += x * Cf[k * 32 + j];
        }
#pragma unroll
        for (int j = 0; j < 32; ++j) acc_s[tid][j] = acc[j] * nr;
        d_s[tid] = d;
    } else {
        d_s[tid] = -1;
    }
    __syncthreads();

    // coalesced atomic phase: each 32-lane group covers one full h-row per iter
    int j  = tid & 31;
    int r0 = tid >> 5;                 // 0..7
#pragma unroll
    for (int it = 0; it < 32; ++it) {
        int r = r0 + (it << 3);        // 0..255, unique per (r0,it)
        int d = d_s[r];
        if (d >= 0) atomicAdd(h + (size_t)d * 32 + j, acc_s[r][j]);
    }
}

__global__ void k3_nf(float* __restrict__ h, const float* __restrict__ Wlf,
                      const float* __restrict__ blf, const int* __restrict__ index2,
                      const int* __restrict__ f2, const int* __restrict__ tar,
                      void* __restrict__ out_bre, float* __restrict__ tacc, int N,
                      const int* __restrict__ flag) {
    int n = blockIdx.x * blockDim.x + threadIdx.x;
    if (n >= N) return;
    int isf32 = flag[0];
    float hr[32];
    const float4* h4 = (const float4*)(h + (size_t)n * 32);
#pragma unroll
    for (int q = 0; q < 8; ++q) {
        float4 v = h4[q];
        hr[q * 4] = v.x; hr[q * 4 + 1] = v.y; hr[q * 4 + 2] = v.z; hr[q * 4 + 3] = v.w;
    }
    float o[32];
#pragma unroll
    for (int j = 0; j < 32; ++j) o[j] = blf[j];
#pragma unroll
    for (int k = 0; k < 32; ++k) {
        float hk = hr[k];
#pragma unroll
        for (int j = 0; j < 32; ++j) o[j] += hk * Wlf[k * 32 + j];
    }
#pragma unroll
    for (int j = 0; j < 32; ++j) o[j] = fmaxf(o[j], 0.f);
    float4* ho = (float4*)(h + (size_t)n * 32);       // in-place: h -> nf
#pragma unroll
    for (int q = 0; q < 8; ++q)
        ho[q] = make_float4(o[q * 4], o[q * 4 + 1], o[q * 4 + 2], o[q * 4 + 3]);
    int b = n / N_PER_C;
    if (index2[n] != 0) {
        int idx = f2[n] + 1;                          // index_offset = 1
        if (idx >= 0 && idx <= NGR) {
            size_t bse = ((size_t)(b * (NGR + 1) + idx)) * 32;
#pragma unroll
            for (int j = 0; j < 32; ++j) ST_OUT(out_bre, bse + j, o[j], isf32);
        }
    }
    if (tar[n] == 1) {
        float* ta = tacc + (size_t)b * 32;
#pragma unroll
        for (int j = 0; j < 32; ++j) atomicAdd(ta + j, o[j]);
    }
}

__global__ __launch_bounds__(256) void k4_attn(const float* __restrict__ nf,
                                               const float* __restrict__ tacc,
                                               const int* __restrict__ index1,
                                               const void* __restrict__ zero_path,
                                               void* __restrict__ out,
                                               size_t off_tar, size_t off_path,
                                               const int* __restrict__ flag) {
    int b = blockIdx.x;
    int tid = threadIdx.x;
    int isf32 = flag[0];
    __shared__ float tg[32];
    __shared__ float red_m[256], red_l[256];
    __shared__ float red_a[256][33];
    if (tid < 32) {
        float v = tacc[(size_t)b * 32 + tid];
        tg[tid] = v;
        ST_OUT(out, off_tar + (size_t)b * 32 + tid, v, isf32);
    }
    __syncthreads();
    float tv[32];
#pragma unroll
    for (int j = 0; j < 32; ++j) tv[j] = tg[j];
    float m = -1e30f, l = 0.f, a[32];
#pragma unroll
    for (int j = 0; j < 32; ++j) a[j] = 0.f;
    for (int r = tid; r < N_PER_C; r += 256) {
        int n = b * N_PER_C + r;
        if (index1[n] == 1) {
            float row[32];
            const float4* nr4 = (const float4*)(nf + (size_t)n * 32);
#pragma unroll
            for (int q = 0; q < 8; ++q) {
                float4 v = nr4[q];
                row[q * 4] = v.x; row[q * 4 + 1] = v.y;
                row[q * 4 + 2] = v.z; row[q * 4 + 3] = v.w;
            }
            float dot = 0.f;
#pragma unroll
            for (int j = 0; j < 32; ++j) dot += row[j] * tv[j];
            if (dot > m) {
                float c = __expf(m - dot);
                l *= c;
#pragma unroll
                for (int j = 0; j < 32; ++j) a[j] *= c;
                m = dot;
            }
            float w = __expf(dot - m);
            l += w;
#pragma unroll
            for (int j = 0; j < 32; ++j) a[j] += w * row[j];
        }
    }
    red_m[tid] = m; red_l[tid] = l;
#pragma unroll
    for (int j = 0; j < 32; ++j) red_a[tid][j] = a[j];
    __syncthreads();
    for (int s = 128; s >= 1; s >>= 1) {
        if (tid < s) {
            float m1 = red_m[tid], m2 = red_m[tid + s];
            float M = fmaxf(m1, m2);
            float c1 = __expf(m1 - M), c2 = __expf(m2 - M);
            red_l[tid] = red_l[tid] * c1 + red_l[tid + s] * c2;
#pragma unroll
            for (int j = 0; j < 32; ++j)
                red_a[tid][j] = red_a[tid][j] * c1 + red_a[tid + s][j] * c2;
            red_m[tid] = M;
        }
        __syncthreads();
    }
    if (tid < 32) {
        float L = red_l[0];
        float o = (L > 0.f) ? (red_a[0][tid] / L) : LD(zero_path, tid, isf32);
        ST_OUT(out, off_path + (size_t)b * 32 + tid, o, isf32);
    }
}

extern "C" void kernel_launch(void* const* d_in, const int* in_sizes, int n_in,
                              void* d_out, int out_size, void* d_ws, size_t ws_size,
                              hipStream_t stream) {
    const void* feat     = d_in[0];
    const void* norm     = d_in[1];
    const void* W_w      = d_in[2];
    const void* b_w      = d_in[3];
    const void* W2       = d_in[4];
    const void* b2v      = d_in[5];
    const void* attn     = d_in[6];
    const void* slw      = d_in[7];
    const void* W_line   = d_in[8];
    const void* b_line   = d_in[9];
    const void* zeroPath = d_in[10];
    const int* src       = (const int*)d_in[11];
    const int* dst       = (const int*)d_in[12];
    const int* etype     = (const int*)d_in[13];
    const int* index1    = (const int*)d_in[14];
    const int* index2    = (const int*)d_in[15];
    const int* f2        = (const int*)d_in[16];
    const int* tar       = (const int*)d_in[17];

    int N  = in_sizes[0] / 32;
    int E  = in_sizes[1];
    int Bn = N / N_PER_C;

    char* base  = (char*)d_ws;
    int* flag   = (int*)base;                      // 64 B reserved
    float* Wwf  = (float*)(base + 64);             // 1024
    float* bwf  = Wwf + 1024;                      // 32
    float* Af   = bwf + 32;                        // 1024
    float* Cf   = Af + 1024;                       // 1024
    float* cbuf = Cf + 1024;                       // 320
    float* attnf= cbuf + NAR * 32;                 // 320
    float* slwf = attnf + NAR * 32;                // 1024
    float* Wlf  = slwf + 1024;                     // 1024
    float* blf  = Wlf + 1024;                      // 32
    float* tacc = blf + 32;                        // Bn*32
    float* h    = tacc + (size_t)Bn * 32;          // N*32
    char*  gp   = (char*)(h + (size_t)N * 32);     // N*64 fp32 or bf16

    size_t fixed_bytes = (size_t)(gp - base);
    int gpf32 = (ws_size >= fixed_bytes + (size_t)N * 64 * 4) ? 1 : 0;

    size_t off_tar  = (size_t)Bn * (NGR + 1) * 32;
    size_t off_path = off_tar + (size_t)Bn * 32;

    k_detect<<<1, 256, 0, stream>>>((const u32*)feat, flag);
    k_zero<<<(out_size + 255) / 256, 256, 0, stream>>>((u32*)d_out, out_size, flag);
    k0_prep<<<4, 256, 0, stream>>>(W_w, b_w, W2, b2v, attn, slw, W_line, b_line,
                                   Wwf, bwf, Af, Cf, cbuf, attnf, slwf, Wlf, blf,
                                   tacc, Bn * 32, flag);
    k1_node<<<(N + 255) / 256, 256, 0, stream>>>(feat, Wwf, bwf, slwf, Af, gp, h, N,
                                                 flag, gpf32);
    k2_edge<<<(E + EPB - 1) / EPB, 256, 0, stream>>>(src, dst, etype, norm, gp, cbuf,
                                                     attnf, Cf, h, E, flag, gpf32);
    k3_nf<<<(N + 255) / 256, 256, 0, stream>>>(h, Wlf, blf, index2, f2, tar,
                                               d_out, tacc, N, flag);
    k4_attn<<<Bn, 256, 0, stream>>>(h, tacc, index1, zeroPath, d_out,
                                    off_tar, off_path, flag);
}

// Round 4
// 443.497 us; speedup vs baseline: 8.2064x; 1.0512x over previous
//
#include <hip/hip_runtime.h>

// CGGCN: relation-gated edge MLP + segment_sum + relation scatter + path attention.
// Dual-dtype I/O (device probe flag); internal compute fp32.
//
// Edge-MLP folding (W2 = [W2a;W2b;W2c]):
//   msg = (c_t + p[src] + (et ⊙ g[src]) @ C) * norm
//   c_t = et@(W2a+W2b)+b2 (per etype), g = feat@W_w+b_w, p = g@(W2a-W2b), C = W2c.
//
// R3: k2 atomics transposed through LDS -> coalesced (one h-row per 32-lane group).
// R4: gp table stored bf16 (halves edge-gather bytes); k2's LDS staging in bf16
//     (17 KB -> 8 blocks/CU, occupancy 32% -> ~80%).

#define N_PER_C 4096
#define NGR 14
#define NAR 10
#define EPB 256          // edges per block in k2

typedef unsigned short u16;
typedef unsigned int u32;

__device__ __forceinline__ float b2f(u16 u) {
    union { u32 i; float f; } x; x.i = ((u32)u) << 16; return x.f;
}
__device__ __forceinline__ u16 f2bf(float f) {
    union { float f; u32 i; } x; x.f = f;
    u32 r = x.i + 0x7fff + ((x.i >> 16) & 1);
    return (u16)(r >> 16);
}
__device__ __forceinline__ float LD(const void* p, size_t i, int isf32) {
    return isf32 ? ((const float*)p)[i] : b2f(((const u16*)p)[i]);
}
__device__ __forceinline__ void ST_OUT(void* p, size_t i, float v, int isf32) {
    if (isf32) ((float*)p)[i] = v;
    else ((u16*)p)[i] = f2bf(v);
}

__global__ void k_detect(const u32* __restrict__ featw, int* __restrict__ flag) {
    __shared__ int cnt;
    if (threadIdx.x == 0) cnt = 0;
    __syncthreads();
    u32 w = featw[threadIdx.x];
    u32 lo = w & 0xffffu;
    u32 e = (lo >> 7) & 0xffu;
    if ((e >= 100 && e <= 140) || lo == 0) atomicAdd(&cnt, 1);
    __syncthreads();
    if (threadIdx.x == 0) flag[0] = (cnt < 128) ? 1 : 0;  // 1 => fp32
}

__global__ void k_zero(u32* __restrict__ out, int out_size, const int* __restrict__ flag) {
    int i = blockIdx.x * blockDim.x + threadIdx.x;
    int words = (flag[0] ? out_size : out_size / 2);
    if (i < words) out[i] = 0;
}

__global__ void k0_prep(const void* W_w, const void* b_w, const void* W2, const void* b2v,
                        const void* attn, const void* slw, const void* W_line, const void* b_line,
                        float* Wwf, float* bwf, float* Af, float* Cf, float* cbuf,
                        float* attnf, float* slwf, float* Wlf, float* blf,
                        float* tacc, int taccN, const int* __restrict__ flag) {
    int j = blockIdx.x * blockDim.x + threadIdx.x;   // 0..1023
    int isf32 = flag[0];
    if (j < 1024) {
        int k = j >> 5, c = j & 31;
        Wwf[j]  = LD(W_w, j, isf32);
        slwf[j] = LD(slw, j, isf32);
        Wlf[j]  = LD(W_line, j, isf32);
        Af[j]   = LD(W2, k * 32 + c, isf32) - LD(W2, (32 + k) * 32 + c, isf32);
        Cf[j]   = LD(W2, (64 + k) * 32 + c, isf32);
    }
    if (j < taccN) tacc[j] = 0.f;
    if (j < NAR * 32) {
        attnf[j] = LD(attn, j, isf32);
        int t = j >> 5, c = j & 31;
        float s = LD(b2v, c, isf32);
        for (int k = 0; k < 32; ++k)
            s += LD(attn, t * 32 + k, isf32) *
                 (LD(W2, k * 32 + c, isf32) + LD(W2, (32 + k) * 32 + c, isf32));
        cbuf[j] = s;
    }
    if (j < 32) { bwf[j] = LD(b_w, j, isf32); blf[j] = LD(b_line, j, isf32); }
}

// per-node: g = feat@Ww+bw, p = g@A, h = feat@slw; gp stored bf16 (64 vals/node)
__global__ void k1_node(const void* __restrict__ feat, const float* __restrict__ Wwf,
                        const float* __restrict__ bwf, const float* __restrict__ slwf,
                        const float* __restrict__ Af, u16* __restrict__ gp,
                        float* __restrict__ h, int N,
                        const int* __restrict__ flag) {
    int n = blockIdx.x * blockDim.x + threadIdx.x;
    if (n >= N) return;
    int isf32 = flag[0];
    float f[32];
    if (isf32) {
        const float4* fr = (const float4*)((const float*)feat + (size_t)n * 32);
#pragma unroll
        for (int q = 0; q < 8; ++q) {
            float4 v = fr[q];
            f[q * 4 + 0] = v.x; f[q * 4 + 1] = v.y; f[q * 4 + 2] = v.z; f[q * 4 + 3] = v.w;
        }
    } else {
        const uint4* fr = (const uint4*)((const u16*)feat + (size_t)n * 32);
#pragma unroll
        for (int q = 0; q < 4; ++q) {
            uint4 v = fr[q];
            u32 ww[4] = {v.x, v.y, v.z, v.w};
#pragma unroll
            for (int r = 0; r < 4; ++r) {
                f[q * 8 + 2 * r]     = b2f((u16)(ww[r] & 0xffff));
                f[q * 8 + 2 * r + 1] = b2f((u16)(ww[r] >> 16));
            }
        }
    }
    float g[32], hh[32];
#pragma unroll
    for (int j = 0; j < 32; ++j) { g[j] = bwf[j]; hh[j] = 0.f; }
#pragma unroll
    for (int k = 0; k < 32; ++k) {
        float fk = f[k];
#pragma unroll
        for (int j = 0; j < 32; ++j) {
            g[j]  += fk * Wwf[k * 32 + j];
            hh[j] += fk * slwf[k * 32 + j];
        }
    }
    float p[32];
#pragma unroll
    for (int j = 0; j < 32; ++j) p[j] = 0.f;
#pragma unroll
    for (int k = 0; k < 32; ++k) {
        float gk = g[k];
#pragma unroll
        for (int j = 0; j < 32; ++j) p[j] += gk * Af[k * 32 + j];
    }
    // pack g|p as bf16 words (2 per u32), 32 u32 = 128 B contiguous
    u32* go = (u32*)(gp + (size_t)n * 64);
#pragma unroll
    for (int q = 0; q < 16; ++q)
        go[q] = (u32)f2bf(g[2 * q]) | ((u32)f2bf(g[2 * q + 1]) << 16);
#pragma unroll
    for (int q = 0; q < 16; ++q)
        go[16 + q] = (u32)f2bf(p[2 * q]) | ((u32)f2bf(p[2 * q + 1]) << 16);
    float4* ho = (float4*)(h + (size_t)n * 32);
#pragma unroll
    for (int q = 0; q < 8; ++q)
        ho[q] = make_float4(hh[q * 4], hh[q * 4 + 1], hh[q * 4 + 2], hh[q * 4 + 3]);
}

// R4: bf16 LDS staging + coalesced atomics
__global__ __launch_bounds__(256) void k2_edge(const int* __restrict__ src,
                        const int* __restrict__ dst,
                        const int* __restrict__ et, const void* __restrict__ norm,
                        const u16* __restrict__ gp, const float* __restrict__ cbuf,
                        const float* __restrict__ attnf, const float* __restrict__ Cf,
                        float* __restrict__ h, int E,
                        const int* __restrict__ flag) {
    __shared__ u16 acc_s[EPB][33];     // bf16 staging; stride 33 (2B banks-ok)
    __shared__ int d_s[EPB];
    int tid = threadIdx.x;
    int e = blockIdx.x * EPB + tid;
    int isf32 = flag[0];

    if (e < E) {
        int s = src[e], d = dst[e], t = et[e];
        float nr = LD(norm, e, isf32);
        float gv[32], pv[32];
        {
            const uint4* gg = (const uint4*)(gp + (size_t)s * 64);
#pragma unroll
            for (int q = 0; q < 4; ++q) {       // g: first 16 u32
                uint4 v = gg[q];
                u32 ww[4] = {v.x, v.y, v.z, v.w};
#pragma unroll
                for (int r = 0; r < 4; ++r) {
                    gv[q * 8 + 2 * r]     = b2f((u16)(ww[r] & 0xffff));
                    gv[q * 8 + 2 * r + 1] = b2f((u16)(ww[r] >> 16));
                }
            }
#pragma unroll
            for (int q = 0; q < 4; ++q) {       // p: next 16 u32
                uint4 v = gg[4 + q];
                u32 ww[4] = {v.x, v.y, v.z, v.w};
#pragma unroll
                for (int r = 0; r < 4; ++r) {
                    pv[q * 8 + 2 * r]     = b2f((u16)(ww[r] & 0xffff));
                    pv[q * 8 + 2 * r + 1] = b2f((u16)(ww[r] >> 16));
                }
            }
        }
        const float4* cb4 = (const float4*)(cbuf + t * 32);
        const float4* at4 = (const float4*)(attnf + t * 32);
        float xg[32], acc[32];
#pragma unroll
        for (int q = 0; q < 8; ++q) {
            float4 av = at4[q];
            xg[q * 4]     = gv[q * 4]     * av.x;
            xg[q * 4 + 1] = gv[q * 4 + 1] * av.y;
            xg[q * 4 + 2] = gv[q * 4 + 2] * av.z;
            xg[q * 4 + 3] = gv[q * 4 + 3] * av.w;
        }
#pragma unroll
        for (int q = 0; q < 8; ++q) {
            float4 cv = cb4[q];
            acc[q * 4]     = cv.x + pv[q * 4];
            acc[q * 4 + 1] = cv.y + pv[q * 4 + 1];
            acc[q * 4 + 2] = cv.z + pv[q * 4 + 2];
            acc[q * 4 + 3] = cv.w + pv[q * 4 + 3];
        }
#pragma unroll
        for (int k = 0; k < 32; ++k) {
            float x = xg[k];
#pragma unroll
            for (int j = 0; j < 32; ++j) acc[j] += x * Cf[k * 32 + j];
        }
#pragma unroll
        for (int j = 0; j < 32; ++j) acc_s[tid][j] = f2bf(acc[j] * nr);
        d_s[tid] = d;
    } else {
        d_s[tid] = -1;
    }
    __syncthreads();

    // coalesced atomic phase: each 32-lane group covers one full h-row per iter
    int j  = tid & 31;
    int r0 = tid >> 5;                 // 0..7
#pragma unroll
    for (int it = 0; it < 32; ++it) {
        int r = r0 + (it << 3);        // 0..255, unique per (r0,it)
        int d = d_s[r];
        if (d >= 0) atomicAdd(h + (size_t)d * 32 + j, b2f(acc_s[r][j]));
    }
}

__global__ void k3_nf(float* __restrict__ h, const float* __restrict__ Wlf,
                      const float* __restrict__ blf, const int* __restrict__ index2,
                      const int* __restrict__ f2, const int* __restrict__ tar,
                      void* __restrict__ out_bre, float* __restrict__ tacc, int N,
                      const int* __restrict__ flag) {
    int n = blockIdx.x * blockDim.x + threadIdx.x;
    if (n >= N) return;
    int isf32 = flag[0];
    float hr[32];
    const float4* h4 = (const float4*)(h + (size_t)n * 32);
#pragma unroll
    for (int q = 0; q < 8; ++q) {
        float4 v = h4[q];
        hr[q * 4] = v.x; hr[q * 4 + 1] = v.y; hr[q * 4 + 2] = v.z; hr[q * 4 + 3] = v.w;
    }
    float o[32];
#pragma unroll
    for (int j = 0; j < 32; ++j) o[j] = blf[j];
#pragma unroll
    for (int k = 0; k < 32; ++k) {
        float hk = hr[k];
#pragma unroll
        for (int j = 0; j < 32; ++j) o[j] += hk * Wlf[k * 32 + j];
    }
#pragma unroll
    for (int j = 0; j < 32; ++j) o[j] = fmaxf(o[j], 0.f);
    float4* ho = (float4*)(h + (size_t)n * 32);       // in-place: h -> nf
#pragma unroll
    for (int q = 0; q < 8; ++q)
        ho[q] = make_float4(o[q * 4], o[q * 4 + 1], o[q * 4 + 2], o[q * 4 + 3]);
    int b = n / N_PER_C;
    if (index2[n] != 0) {
        int idx = f2[n] + 1;                          // index_offset = 1
        if (idx >= 0 && idx <= NGR) {
            size_t bse = ((size_t)(b * (NGR + 1) + idx)) * 32;
#pragma unroll
            for (int j = 0; j < 32; ++j) ST_OUT(out_bre, bse + j, o[j], isf32);
        }
    }
    if (tar[n] == 1) {
        float* ta = tacc + (size_t)b * 32;
#pragma unroll
        for (int j = 0; j < 32; ++j) atomicAdd(ta + j, o[j]);
    }
}

__global__ __launch_bounds__(256) void k4_attn(const float* __restrict__ nf,
                                               const float* __restrict__ tacc,
                                               const int* __restrict__ index1,
                                               const void* __restrict__ zero_path,
                                               void* __restrict__ out,
                                               size_t off_tar, size_t off_path,
                                               const int* __restrict__ flag) {
    int b = blockIdx.x;
    int tid = threadIdx.x;
    int isf32 = flag[0];
    __shared__ float tg[32];
    __shared__ float red_m[256], red_l[256];
    __shared__ float red_a[256][33];
    if (tid < 32) {
        float v = tacc[(size_t)b * 32 + tid];
        tg[tid] = v;
        ST_OUT(out, off_tar + (size_t)b * 32 + tid, v, isf32);
    }
    __syncthreads();
    float tv[32];
#pragma unroll
    for (int j = 0; j < 32; ++j) tv[j] = tg[j];
    float m = -1e30f, l = 0.f, a[32];
#pragma unroll
    for (int j = 0; j < 32; ++j) a[j] = 0.f;
    for (int r = tid; r < N_PER_C; r += 256) {
        int n = b * N_PER_C + r;
        if (index1[n] == 1) {
            float row[32];
            const float4* nr4 = (const float4*)(nf + (size_t)n * 32);
#pragma unroll
            for (int q = 0; q < 8; ++q) {
                float4 v = nr4[q];
                row[q * 4] = v.x; row[q * 4 + 1] = v.y;
                row[q * 4 + 2] = v.z; row[q * 4 + 3] = v.w;
            }
            float dot = 0.f;
#pragma unroll
            for (int j = 0; j < 32; ++j) dot += row[j] * tv[j];
            if (dot > m) {
                float c = __expf(m - dot);
                l *= c;
#pragma unroll
                for (int j = 0; j < 32; ++j) a[j] *= c;
                m = dot;
            }
            float w = __expf(dot - m);
            l += w;
#pragma unroll
            for (int j = 0; j < 32; ++j) a[j] += w * row[j];
        }
    }
    red_m[tid] = m; red_l[tid] = l;
#pragma unroll
    for (int j = 0; j < 32; ++j) red_a[tid][j] = a[j];
    __syncthreads();
    for (int s = 128; s >= 1; s >>= 1) {
        if (tid < s) {
            float m1 = red_m[tid], m2 = red_m[tid + s];
            float M = fmaxf(m1, m2);
            float c1 = __expf(m1 - M), c2 = __expf(m2 - M);
            red_l[tid] = red_l[tid] * c1 + red_l[tid + s] * c2;
#pragma unroll
            for (int j = 0; j < 32; ++j)
                red_a[tid][j] = red_a[tid][j] * c1 + red_a[tid + s][j] * c2;
            red_m[tid] = M;
        }
        __syncthreads();
    }
    if (tid < 32) {
        float L = red_l[0];
        float o = (L > 0.f) ? (red_a[0][tid] / L) : LD(zero_path, tid, isf32);
        ST_OUT(out, off_path + (size_t)b * 32 + tid, o, isf32);
    }
}

extern "C" void kernel_launch(void* const* d_in, const int* in_sizes, int n_in,
                              void* d_out, int out_size, void* d_ws, size_t ws_size,
                              hipStream_t stream) {
    const void* feat     = d_in[0];
    const void* norm     = d_in[1];
    const void* W_w      = d_in[2];
    const void* b_w      = d_in[3];
    const void* W2       = d_in[4];
    const void* b2v      = d_in[5];
    const void* attn     = d_in[6];
    const void* slw      = d_in[7];
    const void* W_line   = d_in[8];
    const void* b_line   = d_in[9];
    const void* zeroPath = d_in[10];
    const int* src       = (const int*)d_in[11];
    const int* dst       = (const int*)d_in[12];
    const int* etype     = (const int*)d_in[13];
    const int* index1    = (const int*)d_in[14];
    const int* index2    = (const int*)d_in[15];
    const int* f2        = (const int*)d_in[16];
    const int* tar       = (const int*)d_in[17];

    int N  = in_sizes[0] / 32;
    int E  = in_sizes[1];
    int Bn = N / N_PER_C;

    char* base  = (char*)d_ws;
    int* flag   = (int*)base;                      // 64 B reserved
    float* Wwf  = (float*)(base + 64);             // 1024
    float* bwf  = Wwf + 1024;                      // 32
    float* Af   = bwf + 32;                        // 1024
    float* Cf   = Af + 1024;                       // 1024
    float* cbuf = Cf + 1024;                       // 320
    float* attnf= cbuf + NAR * 32;                 // 320
    float* slwf = attnf + NAR * 32;                // 1024
    float* Wlf  = slwf + 1024;                     // 1024
    float* blf  = Wlf + 1024;                      // 32
    float* tacc = blf + 32;                        // Bn*32
    float* h    = tacc + (size_t)Bn * 32;          // N*32 fp32
    u16*  gp    = (u16*)(h + (size_t)N * 32);      // N*64 bf16 (g|p)

    size_t off_tar  = (size_t)Bn * (NGR + 1) * 32;
    size_t off_path = off_tar + (size_t)Bn * 32;

    k_detect<<<1, 256, 0, stream>>>((const u32*)feat, flag);
    k_zero<<<(out_size + 255) / 256, 256, 0, stream>>>((u32*)d_out, out_size, flag);
    k0_prep<<<4, 256, 0, stream>>>(W_w, b_w, W2, b2v, attn, slw, W_line, b_line,
                                   Wwf, bwf, Af, Cf, cbuf, attnf, slwf, Wlf, blf,
                                   tacc, Bn * 32, flag);
    k1_node<<<(N + 255) / 256, 256, 0, stream>>>(feat, Wwf, bwf, slwf, Af, gp, h, N,
                                                 flag);
    k2_edge<<<(E + EPB - 1) / EPB, 256, 0, stream>>>(src, dst, etype, norm, gp, cbuf,
                                                     attnf, Cf, h, E, flag);
    k3_nf<<<(N + 255) / 256, 256, 0, stream>>>(h, Wlf, blf, index2, f2, tar,
                                               d_out, tacc, N, flag);
    k4_attn<<<Bn, 256, 0, stream>>>(h, tacc, index1, zeroPath, d_out,
                                    off_tar, off_path, flag);
}

// Round 5
// 369.553 us; speedup vs baseline: 9.8484x; 1.2001x over previous
//
#include <hip/hip_runtime.h>

// CGGCN: relation-gated edge MLP + segment_sum + relation scatter + path attention.
// Dual-dtype I/O (device probe flag); internal compute fp32.
//
// Edge-MLP folding (W2 = [W2a;W2b;W2c]):
//   msg = (c_t + p[src] + (et ⊙ g[src]) @ C) * norm
//   c_t = et@(W2a+W2b)+b2 (per etype), g = feat@W_w+b_w, p = g@(W2a-W2b), C = W2c.
//
// R3: k2 atomics transposed through LDS -> coalesced (full h-rows per wave).
// R4: gp table bf16; bf16 LDS staging.
// R5: h is bf16[N][32]; segment-sum uses global_atomic_pk_add_bf16 (2 bf16 per
//     4-byte RMW) -> halves the TCC atomic-op count, h-row = one 64B line.

#define N_PER_C 4096
#define NGR 14
#define NAR 10
#define EPB 256          // edges per block in k2

typedef unsigned short u16;
typedef unsigned int u32;
typedef short sv2 __attribute__((ext_vector_type(2)));

__device__ __forceinline__ float b2f(u16 u) {
    union { u32 i; float f; } x; x.i = ((u32)u) << 16; return x.f;
}
__device__ __forceinline__ u16 f2bf(float f) {
    union { float f; u32 i; } x; x.f = f;
    u32 r = x.i + 0x7fff + ((x.i >> 16) & 1);
    return (u16)(r >> 16);
}
__device__ __forceinline__ u32 pack2(float a, float b) {
    return (u32)f2bf(a) | ((u32)f2bf(b) << 16);
}
__device__ __forceinline__ float LD(const void* p, size_t i, int isf32) {
    return isf32 ? ((const float*)p)[i] : b2f(((const u16*)p)[i]);
}
__device__ __forceinline__ void ST_OUT(void* p, size_t i, float v, int isf32) {
    if (isf32) ((float*)p)[i] = v;
    else ((u16*)p)[i] = f2bf(v);
}

__device__ __forceinline__ void pk_atomic_add_bf16(u32* addr, u32 val) {
#if __has_builtin(__builtin_amdgcn_global_atomic_fadd_v2bf16)
    union { u32 u; sv2 s; } c; c.u = val;
    __builtin_amdgcn_global_atomic_fadd_v2bf16((sv2*)addr, c.s);
#else
    // CAS fallback (correct, slow)
    u32 old = *addr, assumed;
    do {
        assumed = old;
        float lo = b2f((u16)(assumed & 0xffff)) + b2f((u16)(val & 0xffff));
        float hi = b2f((u16)(assumed >> 16)) + b2f((u16)(val >> 16));
        old = atomicCAS(addr, assumed, pack2(lo, hi));
    } while (old != assumed);
#endif
}

__global__ void k_detect(const u32* __restrict__ featw, int* __restrict__ flag) {
    __shared__ int cnt;
    if (threadIdx.x == 0) cnt = 0;
    __syncthreads();
    u32 w = featw[threadIdx.x];
    u32 lo = w & 0xffffu;
    u32 e = (lo >> 7) & 0xffu;
    if ((e >= 100 && e <= 140) || lo == 0) atomicAdd(&cnt, 1);
    __syncthreads();
    if (threadIdx.x == 0) flag[0] = (cnt < 128) ? 1 : 0;  // 1 => fp32
}

__global__ void k_zero(u32* __restrict__ out, int out_size, const int* __restrict__ flag) {
    int i = blockIdx.x * blockDim.x + threadIdx.x;
    int words = (flag[0] ? out_size : out_size / 2);
    if (i < words) out[i] = 0;
}

__global__ void k0_prep(const void* W_w, const void* b_w, const void* W2, const void* b2v,
                        const void* attn, const void* slw, const void* W_line, const void* b_line,
                        float* Wwf, float* bwf, float* Af, float* Cf, float* cbuf,
                        float* attnf, float* slwf, float* Wlf, float* blf,
                        float* tacc, int taccN, const int* __restrict__ flag) {
    int j = blockIdx.x * blockDim.x + threadIdx.x;   // 0..1023
    int isf32 = flag[0];
    if (j < 1024) {
        int k = j >> 5, c = j & 31;
        Wwf[j]  = LD(W_w, j, isf32);
        slwf[j] = LD(slw, j, isf32);
        Wlf[j]  = LD(W_line, j, isf32);
        Af[j]   = LD(W2, k * 32 + c, isf32) - LD(W2, (32 + k) * 32 + c, isf32);
        Cf[j]   = LD(W2, (64 + k) * 32 + c, isf32);
    }
    if (j < taccN) tacc[j] = 0.f;
    if (j < NAR * 32) {
        attnf[j] = LD(attn, j, isf32);
        int t = j >> 5, c = j & 31;
        float s = LD(b2v, c, isf32);
        for (int k = 0; k < 32; ++k)
            s += LD(attn, t * 32 + k, isf32) *
                 (LD(W2, k * 32 + c, isf32) + LD(W2, (32 + k) * 32 + c, isf32));
        cbuf[j] = s;
    }
    if (j < 32) { bwf[j] = LD(b_w, j, isf32); blf[j] = LD(b_line, j, isf32); }
}

// per-node: g = feat@Ww+bw, p = g@A, h = feat@slw; gp & h stored bf16
__global__ void k1_node(const void* __restrict__ feat, const float* __restrict__ Wwf,
                        const float* __restrict__ bwf, const float* __restrict__ slwf,
                        const float* __restrict__ Af, u16* __restrict__ gp,
                        u16* __restrict__ h, int N,
                        const int* __restrict__ flag) {
    int n = blockIdx.x * blockDim.x + threadIdx.x;
    if (n >= N) return;
    int isf32 = flag[0];
    float f[32];
    if (isf32) {
        const float4* fr = (const float4*)((const float*)feat + (size_t)n * 32);
#pragma unroll
        for (int q = 0; q < 8; ++q) {
            float4 v = fr[q];
            f[q * 4 + 0] = v.x; f[q * 4 + 1] = v.y; f[q * 4 + 2] = v.z; f[q * 4 + 3] = v.w;
        }
    } else {
        const uint4* fr = (const uint4*)((const u16*)feat + (size_t)n * 32);
#pragma unroll
        for (int q = 0; q < 4; ++q) {
            uint4 v = fr[q];
            u32 ww[4] = {v.x, v.y, v.z, v.w};
#pragma unroll
            for (int r = 0; r < 4; ++r) {
                f[q * 8 + 2 * r]     = b2f((u16)(ww[r] & 0xffff));
                f[q * 8 + 2 * r + 1] = b2f((u16)(ww[r] >> 16));
            }
        }
    }
    float g[32], hh[32];
#pragma unroll
    for (int j = 0; j < 32; ++j) { g[j] = bwf[j]; hh[j] = 0.f; }
#pragma unroll
    for (int k = 0; k < 32; ++k) {
        float fk = f[k];
#pragma unroll
        for (int j = 0; j < 32; ++j) {
            g[j]  += fk * Wwf[k * 32 + j];
            hh[j] += fk * slwf[k * 32 + j];
        }
    }
    float p[32];
#pragma unroll
    for (int j = 0; j < 32; ++j) p[j] = 0.f;
#pragma unroll
    for (int k = 0; k < 32; ++k) {
        float gk = g[k];
#pragma unroll
        for (int j = 0; j < 32; ++j) p[j] += gk * Af[k * 32 + j];
    }
    u32* go = (u32*)(gp + (size_t)n * 64);
#pragma unroll
    for (int q = 0; q < 16; ++q) go[q]      = pack2(g[2 * q], g[2 * q + 1]);
#pragma unroll
    for (int q = 0; q < 16; ++q) go[16 + q] = pack2(p[2 * q], p[2 * q + 1]);
    u32* ho = (u32*)(h + (size_t)n * 32);   // self-loop term initializes h
#pragma unroll
    for (int q = 0; q < 16; ++q) ho[q] = pack2(hh[2 * q], hh[2 * q + 1]);
}

// R5: bf16 LDS staging + packed-bf16 coalesced atomics
__global__ __launch_bounds__(256) void k2_edge(const int* __restrict__ src,
                        const int* __restrict__ dst,
                        const int* __restrict__ et, const void* __restrict__ norm,
                        const u16* __restrict__ gp, const float* __restrict__ cbuf,
                        const float* __restrict__ attnf, const float* __restrict__ Cf,
                        u16* __restrict__ h, int E,
                        const int* __restrict__ flag) {
    __shared__ u32 pk_s[EPB][17];      // packed bf16 pairs; stride 17 (conflict-safe)
    __shared__ int d_s[EPB];
    int tid = threadIdx.x;
    int e = blockIdx.x * EPB + tid;
    int isf32 = flag[0];

    if (e < E) {
        int s = src[e], d = dst[e], t = et[e];
        float nr = LD(norm, e, isf32);
        float gv[32], pv[32];
        {
            const uint4* gg = (const uint4*)(gp + (size_t)s * 64);
#pragma unroll
            for (int q = 0; q < 4; ++q) {       // g: first 16 u32
                uint4 v = gg[q];
                u32 ww[4] = {v.x, v.y, v.z, v.w};
#pragma unroll
                for (int r = 0; r < 4; ++r) {
                    gv[q * 8 + 2 * r]     = b2f((u16)(ww[r] & 0xffff));
                    gv[q * 8 + 2 * r + 1] = b2f((u16)(ww[r] >> 16));
                }
            }
#pragma unroll
            for (int q = 0; q < 4; ++q) {       // p: next 16 u32
                uint4 v = gg[4 + q];
                u32 ww[4] = {v.x, v.y, v.z, v.w};
#pragma unroll
                for (int r = 0; r < 4; ++r) {
                    pv[q * 8 + 2 * r]     = b2f((u16)(ww[r] & 0xffff));
                    pv[q * 8 + 2 * r + 1] = b2f((u16)(ww[r] >> 16));
                }
            }
        }
        const float4* cb4 = (const float4*)(cbuf + t * 32);
        const float4* at4 = (const float4*)(attnf + t * 32);
        float xg[32], acc[32];
#pragma unroll
        for (int q = 0; q < 8; ++q) {
            float4 av = at4[q];
            xg[q * 4]     = gv[q * 4]     * av.x;
            xg[q * 4 + 1] = gv[q * 4 + 1] * av.y;
            xg[q * 4 + 2] = gv[q * 4 + 2] * av.z;
            xg[q * 4 + 3] = gv[q * 4 + 3] * av.w;
        }
#pragma unroll
        for (int q = 0; q < 8; ++q) {
            float4 cv = cb4[q];
            acc[q * 4]     = cv.x + pv[q * 4];
            acc[q * 4 + 1] = cv.y + pv[q * 4 + 1];
            acc[q * 4 + 2] = cv.z + pv[q * 4 + 2];
            acc[q * 4 + 3] = cv.w + pv[q * 4 + 3];
        }
#pragma unroll
        for (int k = 0; k < 32; ++k) {
            float x = xg[k];
#pragma unroll
            for (int j = 0; j < 32; ++j) acc[j] += x * Cf[k * 32 + j];
        }
#pragma unroll
        for (int q = 0; q < 16; ++q)
            pk_s[tid][q] = pack2(acc[2 * q] * nr, acc[2 * q + 1] * nr);
        d_s[tid] = d;
    } else {
        d_s[tid] = -1;
    }
    __syncthreads();

    // coalesced pk-atomic phase: 16 lanes cover one 64B h-row (16 u32 RMW ops)
    u32* hw = (u32*)h;
    int w  = tid & 15;
    int r0 = tid >> 4;                 // 0..15
#pragma unroll
    for (int it = 0; it < 16; ++it) {
        int r = r0 + (it << 4);        // 0..255, unique per (r0,it)
        int d = d_s[r];
        if (d >= 0) pk_atomic_add_bf16(hw + (size_t)d * 16 + w, pk_s[r][w]);
    }
}

// nf = relu(h@W_line+b_line); h bf16 in/out (in-place h->nf); scatter + target
__global__ void k3_nf(u16* __restrict__ h, const float* __restrict__ Wlf,
                      const float* __restrict__ blf, const int* __restrict__ index2,
                      const int* __restrict__ f2, const int* __restrict__ tar,
                      void* __restrict__ out_bre, float* __restrict__ tacc, int N,
                      const int* __restrict__ flag) {
    int n = blockIdx.x * blockDim.x + threadIdx.x;
    if (n >= N) return;
    int isf32 = flag[0];
    float hr[32];
    const uint4* h4 = (const uint4*)(h + (size_t)n * 32);
#pragma unroll
    for (int q = 0; q < 4; ++q) {
        uint4 v = h4[q];
        u32 ww[4] = {v.x, v.y, v.z, v.w};
#pragma unroll
        for (int r = 0; r < 4; ++r) {
            hr[q * 8 + 2 * r]     = b2f((u16)(ww[r] & 0xffff));
            hr[q * 8 + 2 * r + 1] = b2f((u16)(ww[r] >> 16));
        }
    }
    float o[32];
#pragma unroll
    for (int j = 0; j < 32; ++j) o[j] = blf[j];
#pragma unroll
    for (int k = 0; k < 32; ++k) {
        float hk = hr[k];
#pragma unroll
        for (int j = 0; j < 32; ++j) o[j] += hk * Wlf[k * 32 + j];
    }
#pragma unroll
    for (int j = 0; j < 32; ++j) o[j] = fmaxf(o[j], 0.f);
    u32* ho = (u32*)(h + (size_t)n * 32);       // in-place: h -> nf (bf16)
#pragma unroll
    for (int q = 0; q < 16; ++q) ho[q] = pack2(o[2 * q], o[2 * q + 1]);
    int b = n / N_PER_C;
    if (index2[n] != 0) {
        int idx = f2[n] + 1;                          // index_offset = 1
        if (idx >= 0 && idx <= NGR) {
            size_t bse = ((size_t)(b * (NGR + 1) + idx)) * 32;
#pragma unroll
            for (int j = 0; j < 32; ++j) ST_OUT(out_bre, bse + j, o[j], isf32);
        }
    }
    if (tar[n] == 1) {
        float* ta = tacc + (size_t)b * 32;
#pragma unroll
        for (int j = 0; j < 32; ++j) atomicAdd(ta + j, o[j]);
    }
}

__global__ __launch_bounds__(256) void k4_attn(const u16* __restrict__ nf,
                                               const float* __restrict__ tacc,
                                               const int* __restrict__ index1,
                                               const void* __restrict__ zero_path,
                                               void* __restrict__ out,
                                               size_t off_tar, size_t off_path,
                                               const int* __restrict__ flag) {
    int b = blockIdx.x;
    int tid = threadIdx.x;
    int isf32 = flag[0];
    __shared__ float tg[32];
    __shared__ float red_m[256], red_l[256];
    __shared__ float red_a[256][33];
    if (tid < 32) {
        float v = tacc[(size_t)b * 32 + tid];
        tg[tid] = v;
        ST_OUT(out, off_tar + (size_t)b * 32 + tid, v, isf32);
    }
    __syncthreads();
    float tv[32];
#pragma unroll
    for (int j = 0; j < 32; ++j) tv[j] = tg[j];
    float m = -1e30f, l = 0.f, a[32];
#pragma unroll
    for (int j = 0; j < 32; ++j) a[j] = 0.f;
    for (int r = tid; r < N_PER_C; r += 256) {
        int n = b * N_PER_C + r;
        if (index1[n] == 1) {
            float row[32];
            const uint4* nr4 = (const uint4*)(nf + (size_t)n * 32);
#pragma unroll
            for (int q = 0; q < 4; ++q) {
                uint4 v = nr4[q];
                u32 ww[4] = {v.x, v.y, v.z, v.w};
#pragma unroll
                for (int rr = 0; rr < 4; ++rr) {
                    row[q * 8 + 2 * rr]     = b2f((u16)(ww[rr] & 0xffff));
                    row[q * 8 + 2 * rr + 1] = b2f((u16)(ww[rr] >> 16));
                }
            }
            float dot = 0.f;
#pragma unroll
            for (int j = 0; j < 32; ++j) dot += row[j] * tv[j];
            if (dot > m) {
                float c = __expf(m - dot);
                l *= c;
#pragma unroll
                for (int j = 0; j < 32; ++j) a[j] *= c;
                m = dot;
            }
            float w = __expf(dot - m);
            l += w;
#pragma unroll
            for (int j = 0; j < 32; ++j) a[j] += w * row[j];
        }
    }
    red_m[tid] = m; red_l[tid] = l;
#pragma unroll
    for (int j = 0; j < 32; ++j) red_a[tid][j] = a[j];
    __syncthreads();
    for (int s = 128; s >= 1; s >>= 1) {
        if (tid < s) {
            float m1 = red_m[tid], m2 = red_m[tid + s];
            float M = fmaxf(m1, m2);
            float c1 = __expf(m1 - M), c2 = __expf(m2 - M);
            red_l[tid] = red_l[tid] * c1 + red_l[tid + s] * c2;
#pragma unroll
            for (int j = 0; j < 32; ++j)
                red_a[tid][j] = red_a[tid][j] * c1 + red_a[tid + s][j] * c2;
            red_m[tid] = M;
        }
        __syncthreads();
    }
    if (tid < 32) {
        float L = red_l[0];
        float o = (L > 0.f) ? (red_a[0][tid] / L) : LD(zero_path, tid, isf32);
        ST_OUT(out, off_path + (size_t)b * 32 + tid, o, isf32);
    }
}

extern "C" void kernel_launch(void* const* d_in, const int* in_sizes, int n_in,
                              void* d_out, int out_size, void* d_ws, size_t ws_size,
                              hipStream_t stream) {
    const void* feat     = d_in[0];
    const void* norm     = d_in[1];
    const void* W_w      = d_in[2];
    const void* b_w      = d_in[3];
    const void* W2       = d_in[4];
    const void* b2v      = d_in[5];
    const void* attn     = d_in[6];
    const void* slw      = d_in[7];
    const void* W_line   = d_in[8];
    const void* b_line   = d_in[9];
    const void* zeroPath = d_in[10];
    const int* src       = (const int*)d_in[11];
    const int* dst       = (const int*)d_in[12];
    const int* etype     = (const int*)d_in[13];
    const int* index1    = (const int*)d_in[14];
    const int* index2    = (const int*)d_in[15];
    const int* f2        = (const int*)d_in[16];
    const int* tar       = (const int*)d_in[17];

    int N  = in_sizes[0] / 32;
    int E  = in_sizes[1];
    int Bn = N / N_PER_C;

    char* base  = (char*)d_ws;
    int* flag   = (int*)base;                      // 64 B reserved
    float* Wwf  = (float*)(base + 64);             // 1024
    float* bwf  = Wwf + 1024;                      // 32
    float* Af   = bwf + 32;                        // 1024
    float* Cf   = Af + 1024;                       // 1024
    float* cbuf = Cf + 1024;                       // 320
    float* attnf= cbuf + NAR * 32;                 // 320
    float* slwf = attnf + NAR * 32;                // 1024
    float* Wlf  = slwf + 1024;                     // 1024
    float* blf  = Wlf + 1024;                      // 32
    float* tacc = blf + 32;                        // Bn*32
    u16*  h     = (u16*)(tacc + (size_t)Bn * 32);  // N*32 bf16 (h, then nf)
    u16*  gp    = h + (size_t)N * 32;              // N*64 bf16 (g|p)

    size_t off_tar  = (size_t)Bn * (NGR + 1) * 32;
    size_t off_path = off_tar + (size_t)Bn * 32;

    k_detect<<<1, 256, 0, stream>>>((const u32*)feat, flag);
    k_zero<<<(out_size + 255) / 256, 256, 0, stream>>>((u32*)d_out, out_size, flag);
    k0_prep<<<4, 256, 0, stream>>>(W_w, b_w, W2, b2v, attn, slw, W_line, b_line,
                                   Wwf, bwf, Af, Cf, cbuf, attnf, slwf, Wlf, blf,
                                   tacc, Bn * 32, flag);
    k1_node<<<(N + 255) / 256, 256, 0, stream>>>(feat, Wwf, bwf, slwf, Af, gp, h, N,
                                                 flag);
    k2_edge<<<(E + EPB - 1) / EPB, 256, 0, stream>>>(src, dst, etype, norm, gp, cbuf,
                                                     attnf, Cf, h, E, flag);
    k3_nf<<<(N + 255) / 256, 256, 0, stream>>>(h, Wlf, blf, index2, f2, tar,
                                               d_out, tacc, N, flag);
    k4_attn<<<Bn, 256, 0, stream>>>(h, tacc, index1, zeroPath, d_out,
                                    off_tar, off_path, flag);
}

// Round 6
// 314.962 us; speedup vs baseline: 11.5554x; 1.1733x over previous
//
#include <hip/hip_runtime.h>

// CGGCN: relation-gated edge MLP + segment_sum + relation scatter + path attention.
// Dual-dtype I/O (per-block device probe); internal compute fp32 / packed fp16.
//
// Edge-MLP folding (W2 = [W2a;W2b;W2c]):
//   msg = (c_t + p[src] + (et ⊙ g[src]) @ C) * norm
//   c_t = et@(W2a+W2b)+b2 (per etype), g = feat@W_w+b_w, p = g@(W2a-W2b), C = W2c.
//
// R3: k2 atomics LDS-transposed -> coalesced full h-rows per wave.
// R5: packed 2-wide atomics (2 values per 4B RMW).
// R6: 8 launches -> 5 (fused prep); k2 message math in packed fp16 (v_pk_fma_f16,
//     C via s_load); h accumulation via global_atomic_fadd_v2f16 (fp16 mantissa
//     restores precision margin vs bf16 atomics).

#define N_PER_C 4096
#define NGR 14
#define NAR 10
#define EPB 256          // edges per block in k2
#define NZB 68           // zero-blocks in prep

typedef unsigned short u16;
typedef unsigned int u32;
typedef _Float16 hv2 __attribute__((ext_vector_type(2)));
union U32H2 { u32 u; hv2 h; };

__device__ __forceinline__ float b2f(u16 u) {
    union { u32 i; float f; } x; x.i = ((u32)u) << 16; return x.f;
}
__device__ __forceinline__ u16 f2bf(float f) {
    union { float f; u32 i; } x; x.f = f;
    u32 r = x.i + 0x7fff + ((x.i >> 16) & 1);
    return (u16)(r >> 16);
}
__device__ __forceinline__ float LD(const void* p, size_t i, int isf32) {
    return isf32 ? ((const float*)p)[i] : b2f(((const u16*)p)[i]);
}
__device__ __forceinline__ void ST_OUT(void* p, size_t i, float v, int isf32) {
    if (isf32) ((float*)p)[i] = v;
    else ((u16*)p)[i] = f2bf(v);
}
__device__ __forceinline__ u32 pkh(float a, float b) {
    U32H2 c; c.h = (hv2){(_Float16)a, (_Float16)b}; return c.u;
}
__device__ __forceinline__ hv2 ash2(u32 w) { U32H2 c; c.u = w; return c.h; }

__device__ __forceinline__ void pk_atomic_add_f16(u32* addr, u32 val) {
#if __has_builtin(__builtin_amdgcn_global_atomic_fadd_v2f16)
    U32H2 c; c.u = val;
    __builtin_amdgcn_global_atomic_fadd_v2f16((hv2*)addr, c.h);
#else
    u32 old = *addr, assumed;
    do {
        assumed = old;
        U32H2 a, v, r; a.u = assumed; v.u = val;
        r.h = a.h + v.h;
        old = atomicCAS(addr, assumed, r.u);
    } while (old != assumed);
#endif
}

__device__ __forceinline__ int probe_flag(const u32* featw) {
    // bf16 data: low u16 of each word has exponent in [100,140] (or zero)
    int cnt = 0;
#pragma unroll 8
    for (int i = 0; i < 256; i += 64) {
        u32 w = featw[i + (threadIdx.x & 63)];
        u32 lo = w & 0xffffu;
        u32 e = (lo >> 7) & 0xffu;
        cnt += ((e >= 100 && e <= 140) || lo == 0) ? 1 : 0;
    }
    // wave-wide vote (64 lanes x 4 samples)
    unsigned long long m = __ballot(cnt >= 3);
    return (__popcll(m) < 32) ? 1 : 0;   // 1 => fp32
}

// ---- fused front: zero d_out (blocks 0..NZB-1) + build tables (block NZB) ----
__global__ __launch_bounds__(256) void k_prep(
        const u32* __restrict__ featw,
        const void* W_w, const void* b_w, const void* W2, const void* b2v,
        const void* attn, const void* slw, const void* W_line, const void* b_line,
        u32* __restrict__ outw, int out_size,
        float* Wwf, float* bwf, float* Af, float* slwf, float* Wlf, float* blf,
        u32* Cf2, u32* at2, u32* cb2,
        float* tacc, int taccN, int* flag) {
    int t = threadIdx.x;
    int b = blockIdx.x;
    int isf32 = probe_flag(featw);
    if (b < NZB) {
        int words = isf32 ? out_size : out_size / 2;
        for (int i = b * 256 + t; i < words; i += NZB * 256) outw[i] = 0;
        return;
    }
    // builder block
    if (t == 0) flag[0] = isf32;
    for (int i = t; i < 1024; i += 256) {
        int k = i >> 5, c = i & 31;
        Wwf[i]  = LD(W_w, i, isf32);
        slwf[i] = LD(slw, i, isf32);
        Wlf[i]  = LD(W_line, i, isf32);
        Af[i]   = LD(W2, k * 32 + c, isf32) - LD(W2, (32 + k) * 32 + c, isf32);
    }
    for (int i = t; i < 512; i += 256) {          // C = W2c as fp16 pairs
        int k = i >> 4, j2 = i & 15;
        Cf2[i] = pkh(LD(W2, (64 + k) * 32 + 2 * j2, isf32),
                     LD(W2, (64 + k) * 32 + 2 * j2 + 1, isf32));
    }
    for (int i = t; i < NAR * 16; i += 256) {     // attn + folded c_t as fp16 pairs
        int tt = i >> 4, j2 = i & 15;
        at2[i] = pkh(LD(attn, tt * 32 + 2 * j2, isf32),
                     LD(attn, tt * 32 + 2 * j2 + 1, isf32));
        float s0 = LD(b2v, 2 * j2, isf32), s1 = LD(b2v, 2 * j2 + 1, isf32);
        for (int k = 0; k < 32; ++k) {
            float a = LD(attn, tt * 32 + k, isf32);
            s0 += a * (LD(W2, k * 32 + 2 * j2, isf32) + LD(W2, (32 + k) * 32 + 2 * j2, isf32));
            s1 += a * (LD(W2, k * 32 + 2 * j2 + 1, isf32) + LD(W2, (32 + k) * 32 + 2 * j2 + 1, isf32));
        }
        cb2[i] = pkh(s0, s1);
    }
    for (int i = t; i < taccN; i += 256) tacc[i] = 0.f;
    if (t < 32) { bwf[t] = LD(b_w, t, isf32); blf[t] = LD(b_line, t, isf32); }
}

// ---- per-node: g = feat@Ww+bw, p = g@A, h = feat@slw; gp & h packed fp16 ----
__global__ void k1_node(const void* __restrict__ feat, const float* __restrict__ Wwf,
                        const float* __restrict__ bwf, const float* __restrict__ slwf,
                        const float* __restrict__ Af, u32* __restrict__ gp,
                        u32* __restrict__ h, int N,
                        const int* __restrict__ flag) {
    int n = blockIdx.x * blockDim.x + threadIdx.x;
    if (n >= N) return;
    int isf32 = flag[0];
    float f[32];
    if (isf32) {
        const float4* fr = (const float4*)((const float*)feat + (size_t)n * 32);
#pragma unroll
        for (int q = 0; q < 8; ++q) {
            float4 v = fr[q];
            f[q * 4 + 0] = v.x; f[q * 4 + 1] = v.y; f[q * 4 + 2] = v.z; f[q * 4 + 3] = v.w;
        }
    } else {
        const uint4* fr = (const uint4*)((const u16*)feat + (size_t)n * 32);
#pragma unroll
        for (int q = 0; q < 4; ++q) {
            uint4 v = fr[q];
            u32 ww[4] = {v.x, v.y, v.z, v.w};
#pragma unroll
            for (int r = 0; r < 4; ++r) {
                f[q * 8 + 2 * r]     = b2f((u16)(ww[r] & 0xffff));
                f[q * 8 + 2 * r + 1] = b2f((u16)(ww[r] >> 16));
            }
        }
    }
    float g[32], hh[32];
#pragma unroll
    for (int j = 0; j < 32; ++j) { g[j] = bwf[j]; hh[j] = 0.f; }
#pragma unroll
    for (int k = 0; k < 32; ++k) {
        float fk = f[k];
#pragma unroll
        for (int j = 0; j < 32; ++j) {
            g[j]  += fk * Wwf[k * 32 + j];
            hh[j] += fk * slwf[k * 32 + j];
        }
    }
    float p[32];
#pragma unroll
    for (int j = 0; j < 32; ++j) p[j] = 0.f;
#pragma unroll
    for (int k = 0; k < 32; ++k) {
        float gk = g[k];
#pragma unroll
        for (int j = 0; j < 32; ++j) p[j] += gk * Af[k * 32 + j];
    }
    u32* go = gp + (size_t)n * 32;
#pragma unroll
    for (int q = 0; q < 16; ++q) go[q]      = pkh(g[2 * q], g[2 * q + 1]);
#pragma unroll
    for (int q = 0; q < 16; ++q) go[16 + q] = pkh(p[2 * q], p[2 * q + 1]);
    u32* ho = h + (size_t)n * 16;            // self-loop term initializes h
#pragma unroll
    for (int q = 0; q < 16; ++q) ho[q] = pkh(hh[2 * q], hh[2 * q + 1]);
}

// ---- edge MLP (packed fp16) + coalesced v2f16 atomics ----
__global__ __launch_bounds__(256) void k2_edge(const int* __restrict__ src,
                        const int* __restrict__ dst,
                        const int* __restrict__ et, const void* __restrict__ norm,
                        const u32* __restrict__ gp, const u32* __restrict__ cb2,
                        const u32* __restrict__ at2, const u32* __restrict__ Cp,
                        u32* __restrict__ h, int E,
                        const int* __restrict__ flag) {
    __shared__ u32 pk_s[EPB][17];      // packed f16 pairs; stride 17
    __shared__ int d_s[EPB];
    int tid = threadIdx.x;
    int e = blockIdx.x * EPB + tid;
    int isf32 = flag[0];

    if (e < E) {
        int s = src[e], d = dst[e], t = et[e];
        float nr = LD(norm, e, isf32);
        u32 gw[16], pw[16], aw[16], cw[16];
        {
            const uint4* gg = (const uint4*)(gp + (size_t)s * 32);
#pragma unroll
            for (int q = 0; q < 4; ++q) {
                uint4 v = gg[q];
                gw[q * 4] = v.x; gw[q * 4 + 1] = v.y; gw[q * 4 + 2] = v.z; gw[q * 4 + 3] = v.w;
            }
#pragma unroll
            for (int q = 0; q < 4; ++q) {
                uint4 v = gg[4 + q];
                pw[q * 4] = v.x; pw[q * 4 + 1] = v.y; pw[q * 4 + 2] = v.z; pw[q * 4 + 3] = v.w;
            }
            const uint4* a4 = (const uint4*)(at2 + t * 16);
            const uint4* c4 = (const uint4*)(cb2 + t * 16);
#pragma unroll
            for (int q = 0; q < 4; ++q) {
                uint4 v = a4[q];
                aw[q * 4] = v.x; aw[q * 4 + 1] = v.y; aw[q * 4 + 2] = v.z; aw[q * 4 + 3] = v.w;
                uint4 w = c4[q];
                cw[q * 4] = w.x; cw[q * 4 + 1] = w.y; cw[q * 4 + 2] = w.z; cw[q * 4 + 3] = w.w;
            }
        }
        hv2 xg2[16], acc2[16];
#pragma unroll
        for (int q = 0; q < 16; ++q) {
            xg2[q]  = ash2(gw[q]) * ash2(aw[q]);   // et ⊙ g[src]
            acc2[q] = ash2(cw[q]) + ash2(pw[q]);   // c_t + p[src]
        }
#pragma unroll
        for (int k = 0; k < 32; ++k) {             // acc += (et⊙g) @ C, pk_fma
            _Float16 xs = xg2[k >> 1][k & 1];
            hv2 xkk = {xs, xs};
#pragma unroll
            for (int j2 = 0; j2 < 16; ++j2)
                acc2[j2] += ash2(Cp[k * 16 + j2]) * xkk;   // Cp wave-uniform -> s_load
        }
        _Float16 nh = (_Float16)nr;
        hv2 nr2 = {nh, nh};
#pragma unroll
        for (int q = 0; q < 16; ++q) {
            U32H2 c; c.h = acc2[q] * nr2;
            pk_s[tid][q] = c.u;
        }
        d_s[tid] = d;
    } else {
        d_s[tid] = -1;
    }
    __syncthreads();

    // coalesced pk-atomic phase: 16 lanes cover one 64B h-row
    int w  = tid & 15;
    int r0 = tid >> 4;                 // 0..15
#pragma unroll
    for (int it = 0; it < 16; ++it) {
        int r = r0 + (it << 4);        // 0..255, unique per (r0,it)
        int d = d_s[r];
        if (d >= 0) pk_atomic_add_f16(h + (size_t)d * 16 + w, pk_s[r][w]);
    }
}

// ---- nf = relu(h@W_line+b_line); h f16 in / nf f16 out; scatter + target ----
__global__ void k3_nf(u32* __restrict__ h, const float* __restrict__ Wlf,
                      const float* __restrict__ blf, const int* __restrict__ index2,
                      const int* __restrict__ f2, const int* __restrict__ tar,
                      void* __restrict__ out_bre, float* __restrict__ tacc, int N,
                      const int* __restrict__ flag) {
    int n = blockIdx.x * blockDim.x + threadIdx.x;
    if (n >= N) return;
    int isf32 = flag[0];
    float hr[32];
    const uint4* h4 = (const uint4*)(h + (size_t)n * 16);
#pragma unroll
    for (int q = 0; q < 4; ++q) {
        uint4 v = h4[q];
        u32 ww[4] = {v.x, v.y, v.z, v.w};
#pragma unroll
        for (int r = 0; r < 4; ++r) {
            hv2 x = ash2(ww[r]);
            hr[q * 8 + 2 * r]     = (float)x[0];
            hr[q * 8 + 2 * r + 1] = (float)x[1];
        }
    }
    float o[32];
#pragma unroll
    for (int j = 0; j < 32; ++j) o[j] = blf[j];
#pragma unroll
    for (int k = 0; k < 32; ++k) {
        float hk = hr[k];
#pragma unroll
        for (int j = 0; j < 32; ++j) o[j] += hk * Wlf[k * 32 + j];
    }
#pragma unroll
    for (int j = 0; j < 32; ++j) o[j] = fmaxf(o[j], 0.f);
    u32* ho = h + (size_t)n * 16;               // in-place: h -> nf (f16)
#pragma unroll
    for (int q = 0; q < 16; ++q) ho[q] = pkh(o[2 * q], o[2 * q + 1]);
    int b = n / N_PER_C;
    if (index2[n] != 0) {
        int idx = f2[n] + 1;                    // index_offset = 1
        if (idx >= 0 && idx <= NGR) {
            size_t bse = ((size_t)(b * (NGR + 1) + idx)) * 32;
#pragma unroll
            for (int j = 0; j < 32; ++j) ST_OUT(out_bre, bse + j, o[j], isf32);
        }
    }
    if (tar[n] == 1) {
        float* ta = tacc + (size_t)b * 32;
#pragma unroll
        for (int j = 0; j < 32; ++j) atomicAdd(ta + j, o[j]);
    }
}

// ---- per-batch path attention (online softmax); nf f16 ----
__global__ __launch_bounds__(256) void k4_attn(const u32* __restrict__ nf,
                                               const float* __restrict__ tacc,
                                               const int* __restrict__ index1,
                                               const void* __restrict__ zero_path,
                                               void* __restrict__ out,
                                               size_t off_tar, size_t off_path,
                                               const int* __restrict__ flag) {
    int b = blockIdx.x;
    int tid = threadIdx.x;
    int isf32 = flag[0];
    __shared__ float tg[32];
    __shared__ float red_m[256], red_l[256];
    __shared__ float red_a[256][33];
    if (tid < 32) {
        float v = tacc[(size_t)b * 32 + tid];
        tg[tid] = v;
        ST_OUT(out, off_tar + (size_t)b * 32 + tid, v, isf32);
    }
    __syncthreads();
    float tv[32];
#pragma unroll
    for (int j = 0; j < 32; ++j) tv[j] = tg[j];
    float m = -1e30f, l = 0.f, a[32];
#pragma unroll
    for (int j = 0; j < 32; ++j) a[j] = 0.f;
    for (int r = tid; r < N_PER_C; r += 256) {
        int n = b * N_PER_C + r;
        if (index1[n] == 1) {
            float row[32];
            const uint4* nr4 = (const uint4*)(nf + (size_t)n * 16);
#pragma unroll
            for (int q = 0; q < 4; ++q) {
                uint4 v = nr4[q];
                u32 ww[4] = {v.x, v.y, v.z, v.w};
#pragma unroll
                for (int rr = 0; rr < 4; ++rr) {
                    hv2 x = ash2(ww[rr]);
                    row[q * 8 + 2 * rr]     = (float)x[0];
                    row[q * 8 + 2 * rr + 1] = (float)x[1];
                }
            }
            float dot = 0.f;
#pragma unroll
            for (int j = 0; j < 32; ++j) dot += row[j] * tv[j];
            if (dot > m) {
                float c = __expf(m - dot);
                l *= c;
#pragma unroll
                for (int j = 0; j < 32; ++j) a[j] *= c;
                m = dot;
            }
            float w = __expf(dot - m);
            l += w;
#pragma unroll
            for (int j = 0; j < 32; ++j) a[j] += w * row[j];
        }
    }
    red_m[tid] = m; red_l[tid] = l;
#pragma unroll
    for (int j = 0; j < 32; ++j) red_a[tid][j] = a[j];
    __syncthreads();
    for (int s = 128; s >= 1; s >>= 1) {
        if (tid < s) {
            float m1 = red_m[tid], m2 = red_m[tid + s];
            float M = fmaxf(m1, m2);
            float c1 = __expf(m1 - M), c2 = __expf(m2 - M);
            red_l[tid] = red_l[tid] * c1 + red_l[tid + s] * c2;
#pragma unroll
            for (int j = 0; j < 32; ++j)
                red_a[tid][j] = red_a[tid][j] * c1 + red_a[tid + s][j] * c2;
            red_m[tid] = M;
        }
        __syncthreads();
    }
    if (tid < 32) {
        float L = red_l[0];
        float o = (L > 0.f) ? (red_a[0][tid] / L) : LD(zero_path, tid, isf32);
        ST_OUT(out, off_path + (size_t)b * 32 + tid, o, isf32);
    }
}

extern "C" void kernel_launch(void* const* d_in, const int* in_sizes, int n_in,
                              void* d_out, int out_size, void* d_ws, size_t ws_size,
                              hipStream_t stream) {
    const void* feat     = d_in[0];
    const void* norm     = d_in[1];
    const void* W_w      = d_in[2];
    const void* b_w      = d_in[3];
    const void* W2       = d_in[4];
    const void* b2v      = d_in[5];
    const void* attn     = d_in[6];
    const void* slw      = d_in[7];
    const void* W_line   = d_in[8];
    const void* b_line   = d_in[9];
    const void* zeroPath = d_in[10];
    const int* src       = (const int*)d_in[11];
    const int* dst       = (const int*)d_in[12];
    const int* etype     = (const int*)d_in[13];
    const int* index1    = (const int*)d_in[14];
    const int* index2    = (const int*)d_in[15];
    const int* f2        = (const int*)d_in[16];
    const int* tar       = (const int*)d_in[17];

    int N  = in_sizes[0] / 32;
    int E  = in_sizes[1];
    int Bn = N / N_PER_C;

    char* base  = (char*)d_ws;
    int* flag   = (int*)base;                      // 64 B reserved
    float* Wwf  = (float*)(base + 64);             // 1024
    float* bwf  = Wwf + 1024;                      // 32
    float* Af   = bwf + 32;                        // 1024
    float* slwf = Af + 1024;                       // 1024
    float* Wlf  = slwf + 1024;                     // 1024
    float* blf  = Wlf + 1024;                      // 32
    u32*  Cf2   = (u32*)(blf + 32);                // 512
    u32*  at2   = Cf2 + 512;                       // 160
    u32*  cb2   = at2 + NAR * 16;                  // 160
    float* tacc = (float*)(cb2 + NAR * 16);        // Bn*32
    u32*  h     = (u32*)(tacc + (size_t)Bn * 32);  // N*16 (f16 pairs; h then nf)
    u32*  gp    = h + (size_t)N * 16;              // N*32 (f16 pairs; g|p)

    size_t off_tar  = (size_t)Bn * (NGR + 1) * 32;
    size_t off_path = off_tar + (size_t)Bn * 32;

    k_prep<<<NZB + 1, 256, 0, stream>>>((const u32*)feat,
                                        W_w, b_w, W2, b2v, attn, slw, W_line, b_line,
                                        (u32*)d_out, out_size,
                                        Wwf, bwf, Af, slwf, Wlf, blf,
                                        Cf2, at2, cb2, tacc, Bn * 32, flag);
    k1_node<<<(N + 255) / 256, 256, 0, stream>>>(feat, Wwf, bwf, slwf, Af, gp, h, N,
                                                 flag);
    k2_edge<<<(E + EPB - 1) / EPB, 256, 0, stream>>>(src, dst, etype, norm, gp, cb2,
                                                     at2, Cf2, h, E, flag);
    k3_nf<<<(N + 255) / 256, 256, 0, stream>>>(h, Wlf, blf, index2, f2, tar,
                                               d_out, tacc, N, flag);
    k4_attn<<<Bn, 256, 0, stream>>>(h, tacc, index1, zeroPath, d_out,
                                    off_tar, off_path, flag);
}